// Round 24
// baseline (107.391 us; speedup 1.0000x reference)
//
#include <hip/hip_runtime.h>
#include <hip/hip_bf16.h>

// spatial_attention: out = weights @ P1 + H @ W2^T + bias ; P1 = H W1^T
//   Domain uniform (runtime-verified) -> weights fast path: w = relu(dval - dist).
//   Base = R23 (best, 106.96us). Changes:
//   (1) k1: W1 fully LDS-RESIDENT (128KB = 4 x R18-format 32KB regions), staged
//       once -> K-loop has ZERO barriers; launch_bounds(512,2) lets regalloc
//       hoist A-loads deep (1 block/CU, acc[2][8] proven no-spill at 512 thr).
//   (2) k0_check folded into k0_pack block 0 (one fewer launch).
//   k2a (wave-per-row weights) and k2b (K=512 big-span GEMM) R23-verbatim.
// Workspace: Wbf 512KB @0 ; flag @512KB ; P1T 32MB @1MB ; weBuf 32MB @33MB

typedef __attribute__((ext_vector_type(4))) float  f32x4;
typedef __attribute__((ext_vector_type(8))) short  bf16x8;
typedef __attribute__((ext_vector_type(4))) short  bf16x4;

#define EPSC 1e-14f

__device__ __forceinline__ short f2bf(float v) {
  __hip_bfloat16 h = __float2bfloat16(v);
  return *reinterpret_cast<short*>(&h);
}
__device__ __forceinline__ void gload16(const void* g, void* l) {
  __builtin_amdgcn_global_load_lds(
      (const __attribute__((address_space(1))) void*)g,
      (__attribute__((address_space(3))) void*)l, 16, 0, 0);
}
__device__ __forceinline__ bf16x8 cvt8(const float* p) {
  f32x4 a = *(const f32x4*)p;
  f32x4 b = *(const f32x4*)(p + 4);
  bf16x8 r;
  r[0] = f2bf(a[0]); r[1] = f2bf(a[1]); r[2] = f2bf(a[2]); r[3] = f2bf(a[3]);
  r[4] = f2bf(b[0]); r[5] = f2bf(b[1]); r[6] = f2bf(b[2]); r[7] = f2bf(b[3]);
  return r;
}

// ---------------- K0: W fp32 -> bf16 ; block 0 also verifies domain uniformity ----------------
__global__ void k0_pack(const float* __restrict__ W, short* __restrict__ Wbf,
                        const float* __restrict__ domain, float* __restrict__ flag) {
  int idx = blockIdx.x * 256 + threadIdx.x;
  f32x4 v = *(const f32x4*)(W + (size_t)idx * 4);
  bf16x4 pk;
  pk[0] = f2bf(v[0]); pk[1] = f2bf(v[1]); pk[2] = f2bf(v[2]); pk[3] = f2bf(v[3]);
  *(bf16x4*)(Wbf + (size_t)idx * 4) = pk;

  if (blockIdx.x == 0) {
    __shared__ int s_ok[4];
    const int t = threadIdx.x;
    float v0 = domain[0];
    bool ok = true;
    for (int x = t; x < 72 * 72; x += 256) ok = ok && (domain[x] == v0);
    unsigned long long m = __ballot(ok);
    if ((t & 63) == 0) s_ok[t >> 6] = (m == ~0ull) ? 1 : 0;
    __syncthreads();
    if (t == 0) {
      flag[0] = v0;
      flag[1] = (s_ok[0] && s_ok[1] && s_ok[2] && s_ok[3]) ? 1.f : 0.f;
    }
  }
}

// ---------------- k2a: pre-scaled weights, wave-per-row (R9-proven) ----------------
__global__ __launch_bounds__(256) void k2a_weights(
    const float* __restrict__ dist, const float* __restrict__ bear,
    const float* __restrict__ head, const float* __restrict__ seqmask,
    const float* __restrict__ domain, const float* __restrict__ uflag,
    short* __restrict__ weBuf) {
  __shared__ float sMask[256];
  const int t = threadIdx.x;
  const int b = blockIdx.x >> 3;
  const int i0 = (blockIdx.x & 7) * 32;
  if (t < 256) sMask[t] = seqmask[b * 256 + t];
  __syncthreads();

  const int w = t >> 6, l = t & 63;
  const int j0 = l * 4;
  const float dval = uflag[0];
  const bool  uni  = uflag[1] != 0.f;
  const f32x4 mj = *(const f32x4*)(sMask + j0);

  f32x4 dv[8];
  #pragma unroll
  for (int rr = 0; rr < 8; ++rr) {
    int i = i0 + w * 8 + rr;
    dv[rr] = *(const f32x4*)(dist + ((size_t)b * 256 + i) * 256 + j0);
  }

  #pragma unroll
  for (int rr = 0; rr < 8; ++rr) {
    const int i = i0 + w * 8 + rr;
    const float mI = sMask[i];
    const size_t base = ((size_t)b * 256 + i) * 256;
    float ev[4];
    float rs = 0.f;
    if (uni) {
      #pragma unroll
      for (int e = 0; e < 4; ++e) {
        float wv = fmaxf(dval - dv[rr][e], 0.f);
        bool valid = (i != j0 + e) && (mI != 0.f) && (mj[e] != 0.f);
        float ex = (wv > 0.f) ? __expf(wv) : 0.f;
        ex = valid ? ex : 0.f;
        rs += ex;
        ev[e] = valid ? (ex + EPSC) : 0.f;
      }
    } else {
      f32x4 bv = *(const f32x4*)(bear + base + j0);
      f32x4 hv = *(const f32x4*)(head + base + j0);
      #pragma unroll
      for (int e = 0; e < 4; ++e) {
        float f1 = fminf(fmaxf(floorf((hv[e] + 2.5f) * 0.2f), 0.f), 71.f);
        float f2 = fminf(fmaxf(floorf((bv[e] + 2.5f) * 0.2f), 0.f), 71.f);
        float wv = fmaxf(domain[(int)(f1 * 72.f + f2)] - dv[rr][e], 0.f);
        bool valid = (i != j0 + e) && (mI != 0.f) && (mj[e] != 0.f);
        float ex = (wv > 0.f) ? __expf(wv) : 0.f;
        ex = valid ? ex : 0.f;
        rs += ex;
        ev[e] = valid ? (ex + EPSC) : 0.f;
      }
    }
    rs += __shfl_xor(rs, 1, 64);
    rs += __shfl_xor(rs, 2, 64);
    rs += __shfl_xor(rs, 4, 64);
    rs += __shfl_xor(rs, 8, 64);
    rs += __shfl_xor(rs, 16, 64);
    rs += __shfl_xor(rs, 32, 64);
    const float scale = 1.0f / (rs + 257.0f * EPSC);
    bf16x4 pk;
    pk[0] = f2bf(ev[0] * scale); pk[1] = f2bf(ev[1] * scale);
    pk[2] = f2bf(ev[2] * scale); pk[3] = f2bf(ev[3] * scale);
    *(bf16x4*)(weBuf + base + j0) = pk;
  }
}

// ---------------- k1_p1t: P1T = (H W1^T)^T, W1 fully LDS-resident ----------------
// grid 512 (XCD-swizzled), block 512, LDS 131072 (4 x 32KB regions) -> 1 block/CU.
// Stage W1 once (16 gload16/thread, L2-hot) -> 1 barrier -> ZERO-barrier K loop.
__global__ __launch_bounds__(512, 2) void k1_p1t(
    const float* __restrict__ H, const short* __restrict__ Wbf,
    short* __restrict__ P1T) {
  extern __shared__ char sm[];                 // 4 regions x [256 d][64 k] bf16
  const int t = threadIdx.x;
  const int x = blockIdx.x;
  const int blk = (x & 7) * 64 + (x >> 3);     // bijective: 512 = 8*64
  const int n0 = blk * 128;
  const int b  = n0 >> 8;
  const int jb = n0 & 255;

  const int wid = t >> 6, l = t & 63;
  const int lr = l & 15, lg = l >> 4;
  const int wr = wid & 3, wc = wid >> 2;
  const int r3 = l >> 3, sl = l & 7;
  const int sswz = (sl ^ r3) * 8;
  const int sw = (lr & 7) << 4;

  const size_t h0 = ((size_t)(n0 + wr * 32 + lr)) * 256;
  const size_t h1 = h0 + 16 * 256;

  // ---- stage all of W1 (k = 0..255) once: 4 regions x 4 sweeps ----
  #pragma unroll
  for (int rg = 0; rg < 4; ++rg) {
    #pragma unroll
    for (int p = 0; p < 4; ++p) {
      int dd = wid * 8 + r3 + 64 * p;
      gload16(Wbf + (size_t)dd * 512 + rg * 64 + sswz,
              sm + rg * 32768 + (wid * 8 + 64 * p) * 128);
    }
  }
  __syncthreads();                             // the only barrier

  f32x4 acc[2][8] = {};

  // ---- K loop: 8 steps of 32, zero barriers (A-loads free to pipeline) ----
  #pragma unroll
  for (int s4 = 0; s4 < 8; ++s4) {
    const int rg = s4 >> 1, sub = s4 & 1;
    const int kg = s4 * 32 + lg * 8;
    bf16x8 av0 = cvt8(H + h0 + kg);
    bf16x8 av1 = cvt8(H + h1 + kg);
    #pragma unroll
    for (int n = 0; n < 8; ++n) {
      const int d = wc * 128 + n * 16 + lr;
      bf16x8 bb = *(const bf16x8*)(sm + rg * 32768 + d * 128 + ((sub * 64 + lg * 16) ^ sw));
      acc[0][n] = __builtin_amdgcn_mfma_f32_16x16x32_bf16(av0, bb, acc[0][n], 0, 0, 0);
      acc[1][n] = __builtin_amdgcn_mfma_f32_16x16x32_bf16(av1, bb, acc[1][n], 0, 0, 0);
    }
  }

  // epilogue: transposed write P1T[b][d][jb + wr*32 + m*16 + lg*4 + r]
  #pragma unroll
  for (int m = 0; m < 2; ++m) {
    #pragma unroll
    for (int n = 0; n < 8; ++n) {
      const int d = wc * 128 + n * 16 + lr;
      f32x4 v = acc[m][n];
      bf16x4 pk;
      pk[0] = f2bf(v[0]); pk[1] = f2bf(v[1]); pk[2] = f2bf(v[2]); pk[3] = f2bf(v[3]);
      *(bf16x4*)(P1T + (size_t)b * 65536 + (size_t)d * 256 + jb + wr * 32 + m * 16 + lg * 4) = pk;
    }
  }
}

// ---------------- k2b: out = weBuf @ P1T + bf16(H) @ W2 + bias, K=512 (R23) ----------------
// grid 512 (XCD-swizzled), block 512, LDS 66560 -> 2 blocks/CU.
// 4 K-quarter rounds: stage 64KB -> bar -> 4 subs (no barriers).
__global__ __launch_bounds__(512, 4) void k2b_gemm(
    const short* __restrict__ weBuf, const short* __restrict__ P1T,
    const short* __restrict__ Wbf, const float* __restrict__ H,
    const float* __restrict__ bias, float* __restrict__ out) {
  extern __shared__ char sm[];
  float* sBias = (float*)(sm + 65536);
  const int t = threadIdx.x;
  const int x = blockIdx.x;
  const int blk = (x & 7) * 64 + (x >> 3);     // bijective: 512 = 8*64
  const int b  = blk >> 1;
  const int i0 = (blk & 1) * 128;

  const int wid = t >> 6, l = t & 63;
  const int lr = l & 15, lg = l >> 4;
  const int wr = wid & 3, wc = wid >> 2;
  const int r3 = l >> 3, sl = l & 7;
  const int sswz = (sl ^ r3) * 8;
  const int sw = (lr & 7) << 4;

  const short* __restrict__ P1b = P1T + (size_t)b * 65536;
  const size_t a0 = ((size_t)b * 256 + i0 + wr * 32 + lr) * 256;
  const size_t a1 = a0 + 16 * 256;

  if (t < 256) sBias[t] = bias[t];

  f32x4 acc[2][8] = {};

  #pragma unroll
  for (int q = 0; q < 4; ++q) {                // K-quarter rounds (k = q*128)
    if (q) __syncthreads();
    #pragma unroll
    for (int rg = 0; rg < 2; ++rg) {
      #pragma unroll
      for (int p = 0; p < 4; ++p) {
        int dd = wid * 8 + r3 + 64 * p;
        if (q < 2)
          gload16(P1b + (size_t)dd * 256 + q * 128 + rg * 64 + sswz,
                  sm + rg * 32768 + (wid * 8 + 64 * p) * 128);
        else
          gload16(Wbf + (size_t)dd * 512 + 256 + (q - 2) * 128 + rg * 64 + sswz,
                  sm + rg * 32768 + (wid * 8 + 64 * p) * 128);
      }
    }
    __syncthreads();
    #pragma unroll
    for (int s4 = 0; s4 < 4; ++s4) {
      const int rg = s4 >> 1, sub = s4 & 1;
      const int ka = q * 128 + s4 * 32 + lg * 8;   // global concat-k 0..511
      bf16x8 av0, av1;
      if (ka < 256) {
        av0 = *(const bf16x8*)(weBuf + a0 + ka);
        av1 = *(const bf16x8*)(weBuf + a1 + ka);
      } else {
        av0 = cvt8(H + a0 + (ka - 256));
        av1 = cvt8(H + a1 + (ka - 256));
      }
      #pragma unroll
      for (int n = 0; n < 8; ++n) {
        const int d = wc * 128 + n * 16 + lr;
        bf16x8 bb = *(const bf16x8*)(sm + rg * 32768 + d * 128 + ((sub * 64 + lg * 16) ^ sw));
        acc[0][n] = __builtin_amdgcn_mfma_f32_16x16x32_bf16(av0, bb, acc[0][n], 0, 0, 0);
        acc[1][n] = __builtin_amdgcn_mfma_f32_16x16x32_bf16(av1, bb, acc[1][n], 0, 0, 0);
      }
    }
  }

  // epilogue: + bias, fp32 store
  #pragma unroll
  for (int m = 0; m < 2; ++m) {
    #pragma unroll
    for (int n = 0; n < 8; ++n) {
      const int d = wc * 128 + n * 16 + lr;
      const float bs = sBias[d];
      #pragma unroll
      for (int r = 0; r < 4; ++r) {
        const int row = i0 + wr * 32 + m * 16 + lg * 4 + r;
        out[((size_t)b * 256 + row) * 256 + d] = acc[m][n][r] + bs;
      }
    }
  }
}

extern "C" void kernel_launch(void* const* d_in, const int* in_sizes, int n_in,
                              void* d_out, int out_size, void* d_ws, size_t ws_size,
                              hipStream_t stream) {
  const float* hidden  = (const float*)d_in[0];
  const float* dist    = (const float*)d_in[1];
  const float* bear    = (const float*)d_in[2];
  const float* head    = (const float*)d_in[3];
  const float* seqmask = (const float*)d_in[4];
  const float* domain  = (const float*)d_in[5];
  const float* W       = (const float*)d_in[6];
  const float* bias    = (const float*)d_in[7];
  float* out = (float*)d_out;

  char* ws = (char*)d_ws;
  short* Wbf   = (short*)ws;                                 // 512 KB
  float* flag  = (float*)(ws + 524288);                      // 2 floats
  short* P1T   = (short*)(ws + (1u << 20));                  // 32 MB
  short* weBuf = (short*)(ws + (1u << 20) + (32u << 20));    // 32 MB

  k0_pack<<<128, 256, 0, stream>>>(W, Wbf, domain, flag);
  k2a_weights<<<2048, 256, 0, stream>>>(dist, bear, head, seqmask, domain, flag, weBuf);
  k1_p1t<<<512, 512, 131072, stream>>>(hidden, Wbf, P1T);
  k2b_gemm<<<512, 512, 66560, stream>>>(weBuf, P1T, Wbf, hidden, bias, out);
}

// Round 25
// 107.287 us; speedup vs baseline: 1.0010x; 1.0010x over previous
//
#include <hip/hip_runtime.h>
#include <hip/hip_bf16.h>

// spatial_attention: out = weights @ P1 + H @ W2^T + bias ; P1 = H W1^T
//   Domain uniform (runtime-verified) -> weights fast path: w = relu(dval - dist).
//   Base = R24. Change: k1's A-operands MANUALLY PREFETCHED into named registers
//   (16 cvt8 = 32 f32x4 loads issued upfront; static indices; zero-barrier K-loop
//   so no drain kills the batch). Fixes the VGPR=48 serial A-load chain.
//   K0  : Wbf = bf16(W) + domain uniformity flag (fused)
//   k2a : weights -> weBuf (pre-scaled bf16), wave-per-row
//   k1  : P1T[b][d][j] = bf16((H W1^T)^T), W1 LDS-resident, A-prefetch
//   k2b : out = weBuf @ P1T + bf16(H) @ W2 + bias, K=512 big-span (R23)
// Workspace: Wbf 512KB @0 ; flag @512KB ; P1T 32MB @1MB ; weBuf 32MB @33MB

typedef __attribute__((ext_vector_type(4))) float  f32x4;
typedef __attribute__((ext_vector_type(8))) short  bf16x8;
typedef __attribute__((ext_vector_type(4))) short  bf16x4;

#define EPSC 1e-14f

__device__ __forceinline__ short f2bf(float v) {
  __hip_bfloat16 h = __float2bfloat16(v);
  return *reinterpret_cast<short*>(&h);
}
__device__ __forceinline__ void gload16(const void* g, void* l) {
  __builtin_amdgcn_global_load_lds(
      (const __attribute__((address_space(1))) void*)g,
      (__attribute__((address_space(3))) void*)l, 16, 0, 0);
}
__device__ __forceinline__ bf16x8 cvt8(const float* p) {
  f32x4 a = *(const f32x4*)p;
  f32x4 b = *(const f32x4*)(p + 4);
  bf16x8 r;
  r[0] = f2bf(a[0]); r[1] = f2bf(a[1]); r[2] = f2bf(a[2]); r[3] = f2bf(a[3]);
  r[4] = f2bf(b[0]); r[5] = f2bf(b[1]); r[6] = f2bf(b[2]); r[7] = f2bf(b[3]);
  return r;
}

// ---------------- K0: W fp32 -> bf16 ; block 0 also verifies domain uniformity ----------------
__global__ void k0_pack(const float* __restrict__ W, short* __restrict__ Wbf,
                        const float* __restrict__ domain, float* __restrict__ flag) {
  int idx = blockIdx.x * 256 + threadIdx.x;
  f32x4 v = *(const f32x4*)(W + (size_t)idx * 4);
  bf16x4 pk;
  pk[0] = f2bf(v[0]); pk[1] = f2bf(v[1]); pk[2] = f2bf(v[2]); pk[3] = f2bf(v[3]);
  *(bf16x4*)(Wbf + (size_t)idx * 4) = pk;

  if (blockIdx.x == 0) {
    __shared__ int s_ok[4];
    const int t = threadIdx.x;
    float v0 = domain[0];
    bool ok = true;
    for (int x = t; x < 72 * 72; x += 256) ok = ok && (domain[x] == v0);
    unsigned long long m = __ballot(ok);
    if ((t & 63) == 0) s_ok[t >> 6] = (m == ~0ull) ? 1 : 0;
    __syncthreads();
    if (t == 0) {
      flag[0] = v0;
      flag[1] = (s_ok[0] && s_ok[1] && s_ok[2] && s_ok[3]) ? 1.f : 0.f;
    }
  }
}

// ---------------- k2a: pre-scaled weights, wave-per-row (R9-proven) ----------------
__global__ __launch_bounds__(256) void k2a_weights(
    const float* __restrict__ dist, const float* __restrict__ bear,
    const float* __restrict__ head, const float* __restrict__ seqmask,
    const float* __restrict__ domain, const float* __restrict__ uflag,
    short* __restrict__ weBuf) {
  __shared__ float sMask[256];
  const int t = threadIdx.x;
  const int b = blockIdx.x >> 3;
  const int i0 = (blockIdx.x & 7) * 32;
  if (t < 256) sMask[t] = seqmask[b * 256 + t];
  __syncthreads();

  const int w = t >> 6, l = t & 63;
  const int j0 = l * 4;
  const float dval = uflag[0];
  const bool  uni  = uflag[1] != 0.f;
  const f32x4 mj = *(const f32x4*)(sMask + j0);

  f32x4 dv[8];
  #pragma unroll
  for (int rr = 0; rr < 8; ++rr) {
    int i = i0 + w * 8 + rr;
    dv[rr] = *(const f32x4*)(dist + ((size_t)b * 256 + i) * 256 + j0);
  }

  #pragma unroll
  for (int rr = 0; rr < 8; ++rr) {
    const int i = i0 + w * 8 + rr;
    const float mI = sMask[i];
    const size_t base = ((size_t)b * 256 + i) * 256;
    float ev[4];
    float rs = 0.f;
    if (uni) {
      #pragma unroll
      for (int e = 0; e < 4; ++e) {
        float wv = fmaxf(dval - dv[rr][e], 0.f);
        bool valid = (i != j0 + e) && (mI != 0.f) && (mj[e] != 0.f);
        float ex = (wv > 0.f) ? __expf(wv) : 0.f;
        ex = valid ? ex : 0.f;
        rs += ex;
        ev[e] = valid ? (ex + EPSC) : 0.f;
      }
    } else {
      f32x4 bv = *(const f32x4*)(bear + base + j0);
      f32x4 hv = *(const f32x4*)(head + base + j0);
      #pragma unroll
      for (int e = 0; e < 4; ++e) {
        float f1 = fminf(fmaxf(floorf((hv[e] + 2.5f) * 0.2f), 0.f), 71.f);
        float f2 = fminf(fmaxf(floorf((bv[e] + 2.5f) * 0.2f), 0.f), 71.f);
        float wv = fmaxf(domain[(int)(f1 * 72.f + f2)] - dv[rr][e], 0.f);
        bool valid = (i != j0 + e) && (mI != 0.f) && (mj[e] != 0.f);
        float ex = (wv > 0.f) ? __expf(wv) : 0.f;
        ex = valid ? ex : 0.f;
        rs += ex;
        ev[e] = valid ? (ex + EPSC) : 0.f;
      }
    }
    rs += __shfl_xor(rs, 1, 64);
    rs += __shfl_xor(rs, 2, 64);
    rs += __shfl_xor(rs, 4, 64);
    rs += __shfl_xor(rs, 8, 64);
    rs += __shfl_xor(rs, 16, 64);
    rs += __shfl_xor(rs, 32, 64);
    const float scale = 1.0f / (rs + 257.0f * EPSC);
    bf16x4 pk;
    pk[0] = f2bf(ev[0] * scale); pk[1] = f2bf(ev[1] * scale);
    pk[2] = f2bf(ev[2] * scale); pk[3] = f2bf(ev[3] * scale);
    *(bf16x4*)(weBuf + base + j0) = pk;
  }
}

// ---------------- k1_p1t: P1T = (H W1^T)^T, W1 LDS-resident + manual A-prefetch ----------------
// grid 512 (XCD-swizzled), block 512, LDS 131072 -> 1 block/CU, zero-barrier K-loop.
// ALL 16 cvt8 A-loads issued upfront into named registers (static indices).
__global__ __launch_bounds__(512, 2) void k1_p1t(
    const float* __restrict__ H, const short* __restrict__ Wbf,
    short* __restrict__ P1T) {
  extern __shared__ char sm[];                 // 4 regions x [256 d][64 k] bf16
  const int t = threadIdx.x;
  const int x = blockIdx.x;
  const int blk = (x & 7) * 64 + (x >> 3);     // bijective: 512 = 8*64
  const int n0 = blk * 128;
  const int b  = n0 >> 8;
  const int jb = n0 & 255;

  const int wid = t >> 6, l = t & 63;
  const int lr = l & 15, lg = l >> 4;
  const int wr = wid & 3, wc = wid >> 2;
  const int r3 = l >> 3, sl = l & 7;
  const int sswz = (sl ^ r3) * 8;
  const int sw = (lr & 7) << 4;

  const size_t h0 = ((size_t)(n0 + wr * 32 + lr)) * 256;
  const size_t h1 = h0 + 16 * 256;

  // ---- stage all of W1 (k = 0..255) once: 4 regions x 4 sweeps ----
  #pragma unroll
  for (int rg = 0; rg < 4; ++rg) {
    #pragma unroll
    for (int p = 0; p < 4; ++p) {
      int dd = wid * 8 + r3 + 64 * p;
      gload16(Wbf + (size_t)dd * 512 + rg * 64 + sswz,
              sm + rg * 32768 + (wid * 8 + 64 * p) * 128);
    }
  }

  // ---- manual A-prefetch: ALL 16 fragments into registers (batched MLP) ----
  bf16x8 avA[2][4], avB[2][4];
  #pragma unroll
  for (int s = 0; s < 4; ++s) {
    avA[0][s] = cvt8(H + h0 + s * 32 + lg * 8);
    avA[1][s] = cvt8(H + h1 + s * 32 + lg * 8);
  }
  #pragma unroll
  for (int s = 0; s < 4; ++s) {
    avB[0][s] = cvt8(H + h0 + 128 + s * 32 + lg * 8);
    avB[1][s] = cvt8(H + h1 + 128 + s * 32 + lg * 8);
  }
  __syncthreads();                             // the only barrier (W1 staged)

  f32x4 acc[2][8] = {};

  // ---- K loop: 8 steps of 32, zero barriers, A already in registers ----
  #pragma unroll
  for (int s = 0; s < 4; ++s) {
    const int rg = s >> 1, sub = s & 1;
    #pragma unroll
    for (int n = 0; n < 8; ++n) {
      const int d = wc * 128 + n * 16 + lr;
      bf16x8 bb = *(const bf16x8*)(sm + rg * 32768 + d * 128 + ((sub * 64 + lg * 16) ^ sw));
      acc[0][n] = __builtin_amdgcn_mfma_f32_16x16x32_bf16(avA[0][s], bb, acc[0][n], 0, 0, 0);
      acc[1][n] = __builtin_amdgcn_mfma_f32_16x16x32_bf16(avA[1][s], bb, acc[1][n], 0, 0, 0);
    }
  }
  #pragma unroll
  for (int s = 0; s < 4; ++s) {
    const int rg = 2 + (s >> 1), sub = s & 1;
    #pragma unroll
    for (int n = 0; n < 8; ++n) {
      const int d = wc * 128 + n * 16 + lr;
      bf16x8 bb = *(const bf16x8*)(sm + rg * 32768 + d * 128 + ((sub * 64 + lg * 16) ^ sw));
      acc[0][n] = __builtin_amdgcn_mfma_f32_16x16x32_bf16(avB[0][s], bb, acc[0][n], 0, 0, 0);
      acc[1][n] = __builtin_amdgcn_mfma_f32_16x16x32_bf16(avB[1][s], bb, acc[1][n], 0, 0, 0);
    }
  }

  // epilogue: transposed write P1T[b][d][jb + wr*32 + m*16 + lg*4 + r]
  #pragma unroll
  for (int m = 0; m < 2; ++m) {
    #pragma unroll
    for (int n = 0; n < 8; ++n) {
      const int d = wc * 128 + n * 16 + lr;
      f32x4 v = acc[m][n];
      bf16x4 pk;
      pk[0] = f2bf(v[0]); pk[1] = f2bf(v[1]); pk[2] = f2bf(v[2]); pk[3] = f2bf(v[3]);
      *(bf16x4*)(P1T + (size_t)b * 65536 + (size_t)d * 256 + jb + wr * 32 + m * 16 + lg * 4) = pk;
    }
  }
}

// ---------------- k2b: out = weBuf @ P1T + bf16(H) @ W2 + bias, K=512 (R23) ----------------
__global__ __launch_bounds__(512, 4) void k2b_gemm(
    const short* __restrict__ weBuf, const short* __restrict__ P1T,
    const short* __restrict__ Wbf, const float* __restrict__ H,
    const float* __restrict__ bias, float* __restrict__ out) {
  extern __shared__ char sm[];
  float* sBias = (float*)(sm + 65536);
  const int t = threadIdx.x;
  const int x = blockIdx.x;
  const int blk = (x & 7) * 64 + (x >> 3);     // bijective: 512 = 8*64
  const int b  = blk >> 1;
  const int i0 = (blk & 1) * 128;

  const int wid = t >> 6, l = t & 63;
  const int lr = l & 15, lg = l >> 4;
  const int wr = wid & 3, wc = wid >> 2;
  const int r3 = l >> 3, sl = l & 7;
  const int sswz = (sl ^ r3) * 8;
  const int sw = (lr & 7) << 4;

  const short* __restrict__ P1b = P1T + (size_t)b * 65536;
  const size_t a0 = ((size_t)b * 256 + i0 + wr * 32 + lr) * 256;
  const size_t a1 = a0 + 16 * 256;

  if (t < 256) sBias[t] = bias[t];

  f32x4 acc[2][8] = {};

  #pragma unroll
  for (int q = 0; q < 4; ++q) {                // K-quarter rounds (k = q*128)
    if (q) __syncthreads();
    #pragma unroll
    for (int rg = 0; rg < 2; ++rg) {
      #pragma unroll
      for (int p = 0; p < 4; ++p) {
        int dd = wid * 8 + r3 + 64 * p;
        if (q < 2)
          gload16(P1b + (size_t)dd * 256 + q * 128 + rg * 64 + sswz,
                  sm + rg * 32768 + (wid * 8 + 64 * p) * 128);
        else
          gload16(Wbf + (size_t)dd * 512 + 256 + (q - 2) * 128 + rg * 64 + sswz,
                  sm + rg * 32768 + (wid * 8 + 64 * p) * 128);
      }
    }
    __syncthreads();
    #pragma unroll
    for (int s4 = 0; s4 < 4; ++s4) {
      const int rg = s4 >> 1, sub = s4 & 1;
      const int ka = q * 128 + s4 * 32 + lg * 8;   // global concat-k 0..511
      bf16x8 av0, av1;
      if (ka < 256) {
        av0 = *(const bf16x8*)(weBuf + a0 + ka);
        av1 = *(const bf16x8*)(weBuf + a1 + ka);
      } else {
        av0 = cvt8(H + a0 + (ka - 256));
        av1 = cvt8(H + a1 + (ka - 256));
      }
      #pragma unroll
      for (int n = 0; n < 8; ++n) {
        const int d = wc * 128 + n * 16 + lr;
        bf16x8 bb = *(const bf16x8*)(sm + rg * 32768 + d * 128 + ((sub * 64 + lg * 16) ^ sw));
        acc[0][n] = __builtin_amdgcn_mfma_f32_16x16x32_bf16(av0, bb, acc[0][n], 0, 0, 0);
        acc[1][n] = __builtin_amdgcn_mfma_f32_16x16x32_bf16(av1, bb, acc[1][n], 0, 0, 0);
      }
    }
  }

  // epilogue: + bias, fp32 store
  #pragma unroll
  for (int m = 0; m < 2; ++m) {
    #pragma unroll
    for (int n = 0; n < 8; ++n) {
      const int d = wc * 128 + n * 16 + lr;
      const float bs = sBias[d];
      #pragma unroll
      for (int r = 0; r < 4; ++r) {
        const int row = i0 + wr * 32 + m * 16 + lg * 4 + r;
        out[((size_t)b * 256 + row) * 256 + d] = acc[m][n][r] + bs;
      }
    }
  }
}

extern "C" void kernel_launch(void* const* d_in, const int* in_sizes, int n_in,
                              void* d_out, int out_size, void* d_ws, size_t ws_size,
                              hipStream_t stream) {
  const float* hidden  = (const float*)d_in[0];
  const float* dist    = (const float*)d_in[1];
  const float* bear    = (const float*)d_in[2];
  const float* head    = (const float*)d_in[3];
  const float* seqmask = (const float*)d_in[4];
  const float* domain  = (const float*)d_in[5];
  const float* W       = (const float*)d_in[6];
  const float* bias    = (const float*)d_in[7];
  float* out = (float*)d_out;

  char* ws = (char*)d_ws;
  short* Wbf   = (short*)ws;                                 // 512 KB
  float* flag  = (float*)(ws + 524288);                      // 2 floats
  short* P1T   = (short*)(ws + (1u << 20));                  // 32 MB
  short* weBuf = (short*)(ws + (1u << 20) + (32u << 20));    // 32 MB

  k0_pack<<<128, 256, 0, stream>>>(W, Wbf, domain, flag);
  k2a_weights<<<2048, 256, 0, stream>>>(dist, bear, head, seqmask, domain, flag, weBuf);
  k1_p1t<<<512, 512, 131072, stream>>>(hidden, Wbf, P1T);
  k2b_gemm<<<512, 512, 66560, stream>>>(weBuf, P1T, Wbf, hidden, bias, out);
}

// Round 26
// 103.002 us; speedup vs baseline: 1.0426x; 1.0416x over previous
//
#include <hip/hip_runtime.h>
#include <hip/hip_bf16.h>

// spatial_attention: out = weights @ P1 + H @ W2^T + bias ; P1 = H W1^T
//   Domain uniform (runtime-verified) -> weights fast path: w = relu(dval - dist).
//   Base = R25. Change: k1 grid 256 (block = batch b, 1 block/CU, 1 round);
//   W1 staged ONCE per block, then BOTH 128-row tiles of b computed back-to-back
//   (no restage, no barrier between tiles -> staging cost amortized 2x).
//   K0  : Wbf = bf16(W) + domain uniformity flag (fused)
//   k2a : weights -> weBuf (pre-scaled bf16), wave-per-row
//   k1  : P1T[b][d][j] = bf16((H W1^T)^T), W1 LDS-resident, A-prefetch per tile
//   k2b : out = weBuf @ P1T + bf16(H) @ W2 + bias, K=512 big-span (R23)
// Workspace: Wbf 512KB @0 ; flag @512KB ; P1T 32MB @1MB ; weBuf 32MB @33MB

typedef __attribute__((ext_vector_type(4))) float  f32x4;
typedef __attribute__((ext_vector_type(8))) short  bf16x8;
typedef __attribute__((ext_vector_type(4))) short  bf16x4;

#define EPSC 1e-14f

__device__ __forceinline__ short f2bf(float v) {
  __hip_bfloat16 h = __float2bfloat16(v);
  return *reinterpret_cast<short*>(&h);
}
__device__ __forceinline__ void gload16(const void* g, void* l) {
  __builtin_amdgcn_global_load_lds(
      (const __attribute__((address_space(1))) void*)g,
      (__attribute__((address_space(3))) void*)l, 16, 0, 0);
}
__device__ __forceinline__ bf16x8 cvt8(const float* p) {
  f32x4 a = *(const f32x4*)p;
  f32x4 b = *(const f32x4*)(p + 4);
  bf16x8 r;
  r[0] = f2bf(a[0]); r[1] = f2bf(a[1]); r[2] = f2bf(a[2]); r[3] = f2bf(a[3]);
  r[4] = f2bf(b[0]); r[5] = f2bf(b[1]); r[6] = f2bf(b[2]); r[7] = f2bf(b[3]);
  return r;
}

// ---------------- K0: W fp32 -> bf16 ; block 0 also verifies domain uniformity ----------------
__global__ void k0_pack(const float* __restrict__ W, short* __restrict__ Wbf,
                        const float* __restrict__ domain, float* __restrict__ flag) {
  int idx = blockIdx.x * 256 + threadIdx.x;
  f32x4 v = *(const f32x4*)(W + (size_t)idx * 4);
  bf16x4 pk;
  pk[0] = f2bf(v[0]); pk[1] = f2bf(v[1]); pk[2] = f2bf(v[2]); pk[3] = f2bf(v[3]);
  *(bf16x4*)(Wbf + (size_t)idx * 4) = pk;

  if (blockIdx.x == 0) {
    __shared__ int s_ok[4];
    const int t = threadIdx.x;
    float v0 = domain[0];
    bool ok = true;
    for (int x = t; x < 72 * 72; x += 256) ok = ok && (domain[x] == v0);
    unsigned long long m = __ballot(ok);
    if ((t & 63) == 0) s_ok[t >> 6] = (m == ~0ull) ? 1 : 0;
    __syncthreads();
    if (t == 0) {
      flag[0] = v0;
      flag[1] = (s_ok[0] && s_ok[1] && s_ok[2] && s_ok[3]) ? 1.f : 0.f;
    }
  }
}

// ---------------- k2a: pre-scaled weights, wave-per-row (R9-proven) ----------------
__global__ __launch_bounds__(256) void k2a_weights(
    const float* __restrict__ dist, const float* __restrict__ bear,
    const float* __restrict__ head, const float* __restrict__ seqmask,
    const float* __restrict__ domain, const float* __restrict__ uflag,
    short* __restrict__ weBuf) {
  __shared__ float sMask[256];
  const int t = threadIdx.x;
  const int b = blockIdx.x >> 3;
  const int i0 = (blockIdx.x & 7) * 32;
  if (t < 256) sMask[t] = seqmask[b * 256 + t];
  __syncthreads();

  const int w = t >> 6, l = t & 63;
  const int j0 = l * 4;
  const float dval = uflag[0];
  const bool  uni  = uflag[1] != 0.f;
  const f32x4 mj = *(const f32x4*)(sMask + j0);

  f32x4 dv[8];
  #pragma unroll
  for (int rr = 0; rr < 8; ++rr) {
    int i = i0 + w * 8 + rr;
    dv[rr] = *(const f32x4*)(dist + ((size_t)b * 256 + i) * 256 + j0);
  }

  #pragma unroll
  for (int rr = 0; rr < 8; ++rr) {
    const int i = i0 + w * 8 + rr;
    const float mI = sMask[i];
    const size_t base = ((size_t)b * 256 + i) * 256;
    float ev[4];
    float rs = 0.f;
    if (uni) {
      #pragma unroll
      for (int e = 0; e < 4; ++e) {
        float wv = fmaxf(dval - dv[rr][e], 0.f);
        bool valid = (i != j0 + e) && (mI != 0.f) && (mj[e] != 0.f);
        float ex = (wv > 0.f) ? __expf(wv) : 0.f;
        ex = valid ? ex : 0.f;
        rs += ex;
        ev[e] = valid ? (ex + EPSC) : 0.f;
      }
    } else {
      f32x4 bv = *(const f32x4*)(bear + base + j0);
      f32x4 hv = *(const f32x4*)(head + base + j0);
      #pragma unroll
      for (int e = 0; e < 4; ++e) {
        float f1 = fminf(fmaxf(floorf((hv[e] + 2.5f) * 0.2f), 0.f), 71.f);
        float f2 = fminf(fmaxf(floorf((bv[e] + 2.5f) * 0.2f), 0.f), 71.f);
        float wv = fmaxf(domain[(int)(f1 * 72.f + f2)] - dv[rr][e], 0.f);
        bool valid = (i != j0 + e) && (mI != 0.f) && (mj[e] != 0.f);
        float ex = (wv > 0.f) ? __expf(wv) : 0.f;
        ex = valid ? ex : 0.f;
        rs += ex;
        ev[e] = valid ? (ex + EPSC) : 0.f;
      }
    }
    rs += __shfl_xor(rs, 1, 64);
    rs += __shfl_xor(rs, 2, 64);
    rs += __shfl_xor(rs, 4, 64);
    rs += __shfl_xor(rs, 8, 64);
    rs += __shfl_xor(rs, 16, 64);
    rs += __shfl_xor(rs, 32, 64);
    const float scale = 1.0f / (rs + 257.0f * EPSC);
    bf16x4 pk;
    pk[0] = f2bf(ev[0] * scale); pk[1] = f2bf(ev[1] * scale);
    pk[2] = f2bf(ev[2] * scale); pk[3] = f2bf(ev[3] * scale);
    *(bf16x4*)(weBuf + base + j0) = pk;
  }
}

// ---------------- k1_p1t: P1T[b] = (H[b] W1^T)^T, W1 staged once, 2 tiles/block ----------------
// grid 256 (block = batch b, XCD-swizzled), block 512, LDS 131072 -> 1 block/CU, 1 round.
__global__ __launch_bounds__(512, 2) void k1_p1t(
    const float* __restrict__ H, const short* __restrict__ Wbf,
    short* __restrict__ P1T) {
  extern __shared__ char sm[];                 // 4 regions x [256 d][64 k] bf16
  const int t = threadIdx.x;
  const int x = blockIdx.x;
  const int b = (x & 7) * 32 + (x >> 3);       // bijective: 256 = 8*32
  const int wid = t >> 6, l = t & 63;
  const int lr = l & 15, lg = l >> 4;
  const int wr = wid & 3, wc = wid >> 2;
  const int r3 = l >> 3, sl = l & 7;
  const int sswz = (sl ^ r3) * 8;
  const int sw = (lr & 7) << 4;

  // ---- stage all of W1 (k = 0..255) once: 4 regions x 4 sweeps ----
  #pragma unroll
  for (int rg = 0; rg < 4; ++rg) {
    #pragma unroll
    for (int p = 0; p < 4; ++p) {
      int dd = wid * 8 + r3 + 64 * p;
      gload16(Wbf + (size_t)dd * 512 + rg * 64 + sswz,
              sm + rg * 32768 + (wid * 8 + 64 * p) * 128);
    }
  }
  __syncthreads();                             // the only barrier

  #pragma unroll
  for (int tile = 0; tile < 2; ++tile) {       // two 128-row tiles of batch b
    const int n0 = b * 256 + tile * 128;
    const int jb = tile * 128;
    const size_t h0 = ((size_t)(n0 + wr * 32 + lr)) * 256;
    const size_t h1 = h0 + 16 * 256;

    // manual A-prefetch: all 16 fragments of this tile into registers
    bf16x8 avA[2][4], avB[2][4];
    #pragma unroll
    for (int s = 0; s < 4; ++s) {
      avA[0][s] = cvt8(H + h0 + s * 32 + lg * 8);
      avA[1][s] = cvt8(H + h1 + s * 32 + lg * 8);
    }
    #pragma unroll
    for (int s = 0; s < 4; ++s) {
      avB[0][s] = cvt8(H + h0 + 128 + s * 32 + lg * 8);
      avB[1][s] = cvt8(H + h1 + 128 + s * 32 + lg * 8);
    }

    f32x4 acc[2][8] = {};
    #pragma unroll
    for (int s = 0; s < 4; ++s) {
      const int rg = s >> 1, sub = s & 1;
      #pragma unroll
      for (int n = 0; n < 8; ++n) {
        const int d = wc * 128 + n * 16 + lr;
        bf16x8 bb = *(const bf16x8*)(sm + rg * 32768 + d * 128 + ((sub * 64 + lg * 16) ^ sw));
        acc[0][n] = __builtin_amdgcn_mfma_f32_16x16x32_bf16(avA[0][s], bb, acc[0][n], 0, 0, 0);
        acc[1][n] = __builtin_amdgcn_mfma_f32_16x16x32_bf16(avA[1][s], bb, acc[1][n], 0, 0, 0);
      }
    }
    #pragma unroll
    for (int s = 0; s < 4; ++s) {
      const int rg = 2 + (s >> 1), sub = s & 1;
      #pragma unroll
      for (int n = 0; n < 8; ++n) {
        const int d = wc * 128 + n * 16 + lr;
        bf16x8 bb = *(const bf16x8*)(sm + rg * 32768 + d * 128 + ((sub * 64 + lg * 16) ^ sw));
        acc[0][n] = __builtin_amdgcn_mfma_f32_16x16x32_bf16(avB[0][s], bb, acc[0][n], 0, 0, 0);
        acc[1][n] = __builtin_amdgcn_mfma_f32_16x16x32_bf16(avB[1][s], bb, acc[1][n], 0, 0, 0);
      }
    }

    // epilogue: transposed write P1T[b][d][jb + wr*32 + m*16 + lg*4 + r]
    #pragma unroll
    for (int m = 0; m < 2; ++m) {
      #pragma unroll
      for (int n = 0; n < 8; ++n) {
        const int d = wc * 128 + n * 16 + lr;
        f32x4 v = acc[m][n];
        bf16x4 pk;
        pk[0] = f2bf(v[0]); pk[1] = f2bf(v[1]); pk[2] = f2bf(v[2]); pk[3] = f2bf(v[3]);
        *(bf16x4*)(P1T + (size_t)b * 65536 + (size_t)d * 256 + jb + wr * 32 + m * 16 + lg * 4) = pk;
      }
    }
    // no barrier needed between tiles: LDS is read-only after the stage
  }
}

// ---------------- k2b: out = weBuf @ P1T + bf16(H) @ W2 + bias, K=512 (R23) ----------------
__global__ __launch_bounds__(512, 4) void k2b_gemm(
    const short* __restrict__ weBuf, const short* __restrict__ P1T,
    const short* __restrict__ Wbf, const float* __restrict__ H,
    const float* __restrict__ bias, float* __restrict__ out) {
  extern __shared__ char sm[];
  float* sBias = (float*)(sm + 65536);
  const int t = threadIdx.x;
  const int x = blockIdx.x;
  const int blk = (x & 7) * 64 + (x >> 3);     // bijective: 512 = 8*64
  const int b  = blk >> 1;
  const int i0 = (blk & 1) * 128;

  const int wid = t >> 6, l = t & 63;
  const int lr = l & 15, lg = l >> 4;
  const int wr = wid & 3, wc = wid >> 2;
  const int r3 = l >> 3, sl = l & 7;
  const int sswz = (sl ^ r3) * 8;
  const int sw = (lr & 7) << 4;

  const short* __restrict__ P1b = P1T + (size_t)b * 65536;
  const size_t a0 = ((size_t)b * 256 + i0 + wr * 32 + lr) * 256;
  const size_t a1 = a0 + 16 * 256;

  if (t < 256) sBias[t] = bias[t];

  f32x4 acc[2][8] = {};

  #pragma unroll
  for (int q = 0; q < 4; ++q) {                // K-quarter rounds (k = q*128)
    if (q) __syncthreads();
    #pragma unroll
    for (int rg = 0; rg < 2; ++rg) {
      #pragma unroll
      for (int p = 0; p < 4; ++p) {
        int dd = wid * 8 + r3 + 64 * p;
        if (q < 2)
          gload16(P1b + (size_t)dd * 256 + q * 128 + rg * 64 + sswz,
                  sm + rg * 32768 + (wid * 8 + 64 * p) * 128);
        else
          gload16(Wbf + (size_t)dd * 512 + 256 + (q - 2) * 128 + rg * 64 + sswz,
                  sm + rg * 32768 + (wid * 8 + 64 * p) * 128);
      }
    }
    __syncthreads();
    #pragma unroll
    for (int s4 = 0; s4 < 4; ++s4) {
      const int rg = s4 >> 1, sub = s4 & 1;
      const int ka = q * 128 + s4 * 32 + lg * 8;   // global concat-k 0..511
      bf16x8 av0, av1;
      if (ka < 256) {
        av0 = *(const bf16x8*)(weBuf + a0 + ka);
        av1 = *(const bf16x8*)(weBuf + a1 + ka);
      } else {
        av0 = cvt8(H + a0 + (ka - 256));
        av1 = cvt8(H + a1 + (ka - 256));
      }
      #pragma unroll
      for (int n = 0; n < 8; ++n) {
        const int d = wc * 128 + n * 16 + lr;
        bf16x8 bb = *(const bf16x8*)(sm + rg * 32768 + d * 128 + ((sub * 64 + lg * 16) ^ sw));
        acc[0][n] = __builtin_amdgcn_mfma_f32_16x16x32_bf16(av0, bb, acc[0][n], 0, 0, 0);
        acc[1][n] = __builtin_amdgcn_mfma_f32_16x16x32_bf16(av1, bb, acc[1][n], 0, 0, 0);
      }
    }
  }

  // epilogue: + bias, fp32 store
  #pragma unroll
  for (int m = 0; m < 2; ++m) {
    #pragma unroll
    for (int n = 0; n < 8; ++n) {
      const int d = wc * 128 + n * 16 + lr;
      const float bs = sBias[d];
      #pragma unroll
      for (int r = 0; r < 4; ++r) {
        const int row = i0 + wr * 32 + m * 16 + lg * 4 + r;
        out[((size_t)b * 256 + row) * 256 + d] = acc[m][n][r] + bs;
      }
    }
  }
}

extern "C" void kernel_launch(void* const* d_in, const int* in_sizes, int n_in,
                              void* d_out, int out_size, void* d_ws, size_t ws_size,
                              hipStream_t stream) {
  const float* hidden  = (const float*)d_in[0];
  const float* dist    = (const float*)d_in[1];
  const float* bear    = (const float*)d_in[2];
  const float* head    = (const float*)d_in[3];
  const float* seqmask = (const float*)d_in[4];
  const float* domain  = (const float*)d_in[5];
  const float* W       = (const float*)d_in[6];
  const float* bias    = (const float*)d_in[7];
  float* out = (float*)d_out;

  char* ws = (char*)d_ws;
  short* Wbf   = (short*)ws;                                 // 512 KB
  float* flag  = (float*)(ws + 524288);                      // 2 floats
  short* P1T   = (short*)(ws + (1u << 20));                  // 32 MB
  short* weBuf = (short*)(ws + (1u << 20) + (32u << 20));    // 32 MB

  k0_pack<<<128, 256, 0, stream>>>(W, Wbf, domain, flag);
  k2a_weights<<<2048, 256, 0, stream>>>(dist, bear, head, seqmask, domain, flag, weBuf);
  k1_p1t<<<256, 512, 131072, stream>>>(hidden, Wbf, P1T);
  k2b_gemm<<<512, 512, 66560, stream>>>(weBuf, P1T, Wbf, hidden, bias, out);
}